// Round 3
// baseline (438.105 us; speedup 1.0000x reference)
//
#include <hip/hip_runtime.h>
#include <hip/hip_bf16.h>

// Problem dims (fixed by reference):
//   x:  [B=16, c_in=64, T=64, N=512] fp32
//   La: [B=16, N=512, N=512] fp32
//   W:  [c_out=64, K*c_in=192] fp32
//   out:[B, 64, T, N] fp32
// Math: out[b,o,t,q] = sum_{c,k} W[o, c*3+k] * z_k[b,c,t,q]
//   z0 = x ; z1 = x @ La^T ; z2 = 2*(x @ (La@La)^T) - x   [Chebyshev]
// v4: La2 = La@La precomputed (tiny GEMM), then ONE fused big GEMM computes
// z1 and z2 sharing the staged A-tiles -> 32 MFMA per sync phase.

#define B_   16
#define CIN  64
#define T_   64
#define N_   512
#define M_   4096   // CIN*T_ rows per batch
#define KDIM 512
#define COUT 64

typedef __bf16 bf16x8 __attribute__((ext_vector_type(8)));
typedef float  floatx4 __attribute__((ext_vector_type(4)));

__device__ __forceinline__ float bf2f(unsigned short u) {
    unsigned int v = ((unsigned int)u) << 16;
    return __builtin_bit_cast(float, v);
}
__device__ __forceinline__ unsigned short f2bf(float f) {
    unsigned int u = __builtin_bit_cast(unsigned int, f);
    unsigned int lsb = (u >> 16) & 1u;
    u += 0x7fffu + lsb;           // round-to-nearest-even
    return (unsigned short)(u >> 16);
}

// async global->LDS, 16B per lane; LDS dest = wave-uniform base + lane*16
#define GLOAD_LDS16(gp, lp)                                                  \
    __builtin_amdgcn_global_load_lds(                                        \
        (const __attribute__((address_space(1))) void*)(gp),                 \
        (__attribute__((address_space(3))) void*)(lp), 16, 0, 0)

// ---- K0a: fp32 -> bf16 convert, 8 elems/thread ----
__global__ __launch_bounds__(256) void cvt_f32_bf16(
    const float* __restrict__ src, unsigned short* __restrict__ dst, int n)
{
    int i = (blockIdx.x * 256 + threadIdx.x) * 8;
    if (i + 8 <= n) {
        float4 a = *(const float4*)(src + i);
        float4 b = *(const float4*)(src + i + 4);
        union { unsigned short s[8]; uint4 u; } o;
        o.s[0] = f2bf(a.x); o.s[1] = f2bf(a.y); o.s[2] = f2bf(a.z); o.s[3] = f2bf(a.w);
        o.s[4] = f2bf(b.x); o.s[5] = f2bf(b.y); o.s[6] = f2bf(b.z); o.s[7] = f2bf(b.w);
        *(uint4*)(dst + i) = o.u;
    }
}

// ---- K0b: La fp32 -> bf16 row-major AND bf16 transposed, one pass ----
// grid (8 col-tiles, 8 row-tiles, 16 batches), 64x64 tile per block.
__global__ __launch_bounds__(256) void cvt_la_dual(
    const float* __restrict__ La,
    unsigned short* __restrict__ Lab,
    unsigned short* __restrict__ LaT)
{
    __shared__ unsigned short t64[64][68];   // +4 pad breaks bank conflicts
    int b  = blockIdx.z;
    int r0 = blockIdx.y * 64;
    int c0 = blockIdx.x * 64;
    int t   = threadIdx.x;
    int row = t >> 2;
    int cg  = (t & 3) * 16;

    const float* src = La + (size_t)b * N_ * N_ + (size_t)(r0 + row) * N_ + c0 + cg;
    unsigned short s[16];
#pragma unroll
    for (int u = 0; u < 4; u++) {
        float4 f = *(const float4*)(src + u * 4);
        s[u * 4 + 0] = f2bf(f.x); s[u * 4 + 1] = f2bf(f.y);
        s[u * 4 + 2] = f2bf(f.z); s[u * 4 + 3] = f2bf(f.w);
    }
    // row-major bf16 out (coalesced)
    union { unsigned short h[8]; uint4 u; } p0, p1;
#pragma unroll
    for (int u = 0; u < 8; u++) { p0.h[u] = s[u]; p1.h[u] = s[8 + u]; }
    unsigned short* d0 = Lab + (size_t)b * N_ * N_ + (size_t)(r0 + row) * N_ + c0 + cg;
    *(uint4*)d0 = p0.u;
    *(uint4*)(d0 + 8) = p1.u;
    // stash to LDS, read back transposed
#pragma unroll
    for (int u = 0; u < 16; u++) t64[row][cg + u] = s[u];
    __syncthreads();
    int col = t >> 2;
    int rg  = (t & 3) * 16;
    union { unsigned short h[8]; uint4 u; } q0, q1;
#pragma unroll
    for (int u = 0; u < 8; u++) { q0.h[u] = t64[rg + u][col]; q1.h[u] = t64[rg + 8 + u][col]; }
    unsigned short* d1 = LaT + (size_t)b * N_ * N_ + (size_t)(c0 + col) * N_ + r0 + rg;
    *(uint4*)d1 = q0.u;
    *(uint4*)(d1 + 8) = q1.u;
}

// ---- K0c: repack W[o][c*3+k] -> Wb[o][j=k*64+c] bf16 (A-operand layout) ----
__global__ __launch_bounds__(256) void pack_w(
    const float* __restrict__ W, unsigned short* __restrict__ Wb)
{
    int idx = threadIdx.x + blockIdx.x * 256;   // idx = o*192 + j
    if (idx < 64 * 192) {
        int o = idx / 192, j = idx % 192;
        int c = j & 63, k = j >> 6;
        Wb[idx] = f2bf(W[o * 192 + c * 3 + k]);
    }
}

#define BM 128
#define BN 128
#define BK 32
#define KIT  (KDIM / BK)     // 16 K-steps
#define SBUF (BM * BK)       // 4096 ushorts per buffer per matrix

// ---- K1: La2[q][n] = sum_p La[q,p] * LaT[n,p]  (M=512, 16 blocks/batch) ----
__global__ __launch_bounds__(256) void gemm_la2(
    const unsigned short* __restrict__ A,
    const unsigned short* __restrict__ Bm,
    unsigned short* __restrict__ C)
{
    // 256 blocks: h&7 = XCD, each XCD owns 2 batches x 16 blocks
    int h     = blockIdx.x;
    int g     = h & 7;
    int idx   = h >> 3;                 // 0..31
    int batch = g * 2 + (idx >> 4);
    int local = idx & 15;
    int n0    = (local & 3) * BN;
    int m0    = (local >> 2) * BM;

    A  += (size_t)batch * N_ * KDIM;
    Bm += (size_t)batch * N_ * KDIM;
    C  += (size_t)batch * N_ * N_;

    __shared__ __align__(16) unsigned short As[3 * SBUF];
    __shared__ __align__(16) unsigned short Bs[3 * SBUF];

    int tid  = threadIdx.x;
    int lane = tid & 63;
    int wave = tid >> 6;
    int wm   = (wave >> 1) * 64;
    int wn   = (wave & 1) * 64;
    int l15  = lane & 15;
    int quad = lane >> 4;

    int r16 = lane >> 2;
    int sch = lane & 3;
    int gch = sch ^ ((r16 >> 1) & 3);

    const unsigned short* gA0 = A  + (size_t)(m0 + wave * 16 + r16) * KDIM + gch * 8;
    const unsigned short* gA1 = gA0 + (size_t)64 * KDIM;
    const unsigned short* gB0 = Bm + (size_t)(n0 + wave * 16 + r16) * KDIM + gch * 8;
    const unsigned short* gB1 = gB0 + (size_t)64 * KDIM;

    int dA0 = (wave * 16) * BK;
    int dA1 = (64 + wave * 16) * BK;

#define STAGE2(kk, bo) do {                                       \
        GLOAD_LDS16(gA0 + (kk) * BK, &As[(bo) + dA0]);            \
        GLOAD_LDS16(gA1 + (kk) * BK, &As[(bo) + dA1]);            \
        GLOAD_LDS16(gB0 + (kk) * BK, &Bs[(bo) + dA0]);            \
        GLOAD_LDS16(gB1 + (kk) * BK, &Bs[(bo) + dA1]);            \
    } while (0)

    int aoff[4], boff[4];
    int sl = quad ^ ((l15 >> 1) & 3);
#pragma unroll
    for (int im = 0; im < 4; im++) aoff[im] = (wm + im * 16 + l15) * BK + sl * 8;
#pragma unroll
    for (int jn = 0; jn < 4; jn++) boff[jn] = (wn + jn * 16 + l15) * BK + sl * 8;

    floatx4 acc[4][4];
#pragma unroll
    for (int i = 0; i < 4; i++)
#pragma unroll
        for (int j = 0; j < 4; j++) acc[i][j] = (floatx4)0.0f;

    STAGE2(0, 0);
    STAGE2(1, SBUF);

#pragma unroll
    for (int k = 0; k < KIT; ++k) {
        if (k < KIT - 1) asm volatile("s_waitcnt vmcnt(4)" ::: "memory");
        else             asm volatile("s_waitcnt vmcnt(0)" ::: "memory");
        __builtin_amdgcn_s_barrier();
        if (k + 2 < KIT) STAGE2(k + 2, ((k + 2) % 3) * SBUF);

        const int cb = (k % 3) * SBUF;
        bf16x8 af[4], bf[4];
#pragma unroll
        for (int im = 0; im < 4; im++)
            af[im] = __builtin_bit_cast(bf16x8, *(const uint4*)&As[cb + aoff[im]]);
#pragma unroll
        for (int jn = 0; jn < 4; jn++)
            bf[jn] = __builtin_bit_cast(bf16x8, *(const uint4*)&Bs[cb + boff[jn]]);
#pragma unroll
        for (int im = 0; im < 4; im++)
#pragma unroll
            for (int jn = 0; jn < 4; jn++)
                acc[im][jn] = __builtin_amdgcn_mfma_f32_16x16x32_bf16(
                    af[im], bf[jn], acc[im][jn], 0, 0, 0);
    }
#undef STAGE2

#pragma unroll
    for (int im = 0; im < 4; im++)
#pragma unroll
        for (int jn = 0; jn < 4; jn++) {
            int c = n0 + wn + jn * 16 + l15;
#pragma unroll
            for (int r = 0; r < 4; r++) {
                int m = m0 + wm + im * 16 + quad * 4 + r;
                C[(size_t)m * N_ + c] = f2bf(acc[im][jn][r]);
            }
        }
}

// ---- K2: fused big GEMM: z1 = X@La^T, z2 = 2*(X@La2^T) - X ----
// One staged A-tile feeds TWO B-operands -> 32 MFMA per sync phase.
__global__ __launch_bounds__(256) void gemm_fused(
    const unsigned short* __restrict__ A,
    const unsigned short* __restrict__ B1,
    const unsigned short* __restrict__ B2,
    unsigned short* __restrict__ Z1,
    unsigned short* __restrict__ Z2)
{
    // 2048 blocks: h&7 = XCD, each XCD owns 2 batches x 128 blocks
    int h     = blockIdx.x;
    int g     = h & 7;
    int idx   = h >> 3;                 // 0..255
    int batch = g * 2 + (idx >> 7);
    int local = idx & 127;
    int n0    = (local & 3) * BN;
    int m0    = (local >> 2) * BM;

    A  += (size_t)batch * M_ * KDIM;
    B1 += (size_t)batch * N_ * KDIM;
    B2 += (size_t)batch * N_ * KDIM;
    Z1 += (size_t)batch * M_ * N_;
    Z2 += (size_t)batch * M_ * N_;

    __shared__ __align__(16) unsigned short As [3 * SBUF];   // 24 KB
    __shared__ __align__(16) unsigned short Bs1[3 * SBUF];   // 24 KB
    __shared__ __align__(16) unsigned short Bs2[3 * SBUF];   // 24 KB

    int tid  = threadIdx.x;
    int lane = tid & 63;
    int wave = tid >> 6;
    int wm   = (wave >> 1) * 64;
    int wn   = (wave & 1) * 64;
    int l15  = lane & 15;
    int quad = lane >> 4;

    // staging: lane l -> row (wave*16 + l>>2), dest slot l&3; source chunk
    // xor-swizzled with (row>>1)&3 so b128 reads are bank-conflict-free.
    int r16 = lane >> 2;
    int sch = lane & 3;
    int gch = sch ^ ((r16 >> 1) & 3);

    const unsigned short* gA0  = A  + (size_t)(m0 + wave * 16 + r16) * KDIM + gch * 8;
    const unsigned short* gA1  = gA0 + (size_t)64 * KDIM;
    const unsigned short* gB10 = B1 + (size_t)(n0 + wave * 16 + r16) * KDIM + gch * 8;
    const unsigned short* gB11 = gB10 + (size_t)64 * KDIM;
    const unsigned short* gB20 = B2 + (size_t)(n0 + wave * 16 + r16) * KDIM + gch * 8;
    const unsigned short* gB21 = gB20 + (size_t)64 * KDIM;

    int d0 = (wave * 16) * BK;
    int d1 = (64 + wave * 16) * BK;

#define STAGE6(kk, bo) do {                                        \
        GLOAD_LDS16(gA0  + (kk) * BK, &As [(bo) + d0]);            \
        GLOAD_LDS16(gA1  + (kk) * BK, &As [(bo) + d1]);            \
        GLOAD_LDS16(gB10 + (kk) * BK, &Bs1[(bo) + d0]);            \
        GLOAD_LDS16(gB11 + (kk) * BK, &Bs1[(bo) + d1]);            \
        GLOAD_LDS16(gB20 + (kk) * BK, &Bs2[(bo) + d0]);            \
        GLOAD_LDS16(gB21 + (kk) * BK, &Bs2[(bo) + d1]);            \
    } while (0)

    int aoff[4], boff[4];
    int sl = quad ^ ((l15 >> 1) & 3);
#pragma unroll
    for (int im = 0; im < 4; im++) aoff[im] = (wm + im * 16 + l15) * BK + sl * 8;
#pragma unroll
    for (int jn = 0; jn < 4; jn++) boff[jn] = (wn + jn * 16 + l15) * BK + sl * 8;

    floatx4 acc1[4][4], acc2[4][4];
#pragma unroll
    for (int i = 0; i < 4; i++)
#pragma unroll
        for (int j = 0; j < 4; j++) { acc1[i][j] = (floatx4)0.0f; acc2[i][j] = (floatx4)0.0f; }

    // prologue: tiles 0 and 1 in flight (12 loads)
    STAGE6(0, 0);
    STAGE6(1, SBUF);

#pragma unroll
    for (int k = 0; k < KIT; ++k) {
        // wait tile k's 6 loads; keep tile k+1's 6 in flight
        if (k < KIT - 1) asm volatile("s_waitcnt vmcnt(6)" ::: "memory");
        else             asm volatile("s_waitcnt vmcnt(0)" ::: "memory");
        __builtin_amdgcn_s_barrier();
        if (k + 2 < KIT) STAGE6(k + 2, ((k + 2) % 3) * SBUF);

        const int cb = (k % 3) * SBUF;
        bf16x8 af[4], bf1[4], bf2[4];
#pragma unroll
        for (int im = 0; im < 4; im++)
            af[im] = __builtin_bit_cast(bf16x8, *(const uint4*)&As[cb + aoff[im]]);
#pragma unroll
        for (int jn = 0; jn < 4; jn++) {
            bf1[jn] = __builtin_bit_cast(bf16x8, *(const uint4*)&Bs1[cb + boff[jn]]);
            bf2[jn] = __builtin_bit_cast(bf16x8, *(const uint4*)&Bs2[cb + boff[jn]]);
        }
#pragma unroll
        for (int im = 0; im < 4; im++)
#pragma unroll
            for (int jn = 0; jn < 4; jn++) {
                acc1[im][jn] = __builtin_amdgcn_mfma_f32_16x16x32_bf16(
                    af[im], bf1[jn], acc1[im][jn], 0, 0, 0);
                acc2[im][jn] = __builtin_amdgcn_mfma_f32_16x16x32_bf16(
                    af[im], bf2[jn], acc2[im][jn], 0, 0, 0);
            }
    }
#undef STAGE6

    // epilogue: z1 = acc1 ; z2 = 2*acc2 - x   (C/D: col=l15, row=quad*4+r)
    const unsigned short* Xb = A;   // A is xb for this batch already
#pragma unroll
    for (int im = 0; im < 4; im++)
#pragma unroll
        for (int jn = 0; jn < 4; jn++) {
            int c = n0 + wn + jn * 16 + l15;
#pragma unroll
            for (int r = 0; r < 4; r++) {
                int m = m0 + wm + im * 16 + quad * 4 + r;
                size_t idx2 = (size_t)m * N_ + c;
                Z1[idx2] = f2bf(acc1[im][jn][r]);
                Z2[idx2] = f2bf(2.0f * acc2[im][jn][r] - bf2f(Xb[idx2]));
            }
        }
}

// ---- K3: projection as MFMA GEMM (round-0 proven version) ----
// Per batch: C[o=64][n=tq=32768] = Wb[64][192] @ D[192][n],
// D rows j=k*64+c -> z_k row c. B-fragments need D^T[n][j]: stage 32j x 256n
// chunks transposed in LDS (pitch 40 -> 16B-aligned b128 reads, 2-way max).
#define PJ_PITCH 40

__global__ __launch_bounds__(256) void proj(
    const unsigned short* __restrict__ xb,
    const unsigned short* __restrict__ z1b,
    const unsigned short* __restrict__ z2b,
    const unsigned short* __restrict__ Wb,
    float* __restrict__ out)
{
    __shared__ __align__(16) unsigned short Ds[256 * PJ_PITCH];   // 20 KB

    int b  = blockIdx.y;
    int n0 = blockIdx.x * 256;
    int tid  = threadIdx.x;
    int lane = tid & 63;
    int wave = tid >> 6;
    int l15  = lane & 15;
    int quad = lane >> 4;

    size_t boff = (size_t)b * M_ * N_ + n0;
    const unsigned short* zp[3] = { xb + boff, z1b + boff, z2b + boff };

    bf16x8 wf[6];
#pragma unroll
    for (int kc = 0; kc < 6; kc++)
        wf[kc] = __builtin_bit_cast(bf16x8,
            *(const uint4*)(Wb + (size_t)(wave * 16 + l15) * 192 + kc * 32 + quad * 8));

    floatx4 acc[16];
#pragma unroll
    for (int i = 0; i < 16; i++) acc[i] = (floatx4)0.0f;

    int jl  = tid & 31;
    int nc0 = (tid >> 5) * 8;

    for (int kc = 0; kc < 6; kc++) {
        const unsigned short* src =
            zp[kc >> 1] + (size_t)((kc & 1) * 32 + jl) * (T_ * N_) + nc0;
        uint4 v[4];
#pragma unroll
        for (int u = 0; u < 4; u++) v[u] = *(const uint4*)(src + u * 64);

        __syncthreads();
#pragma unroll
        for (int u = 0; u < 4; u++) {
            unsigned short* d = &Ds[(size_t)(nc0 + u * 64) * PJ_PITCH + jl];
            unsigned int w0 = v[u].x, w1 = v[u].y, w2 = v[u].z, w3 = v[u].w;
            d[0 * PJ_PITCH] = (unsigned short)w0;
            d[1 * PJ_PITCH] = (unsigned short)(w0 >> 16);
            d[2 * PJ_PITCH] = (unsigned short)w1;
            d[3 * PJ_PITCH] = (unsigned short)(w1 >> 16);
            d[4 * PJ_PITCH] = (unsigned short)w2;
            d[5 * PJ_PITCH] = (unsigned short)(w2 >> 16);
            d[6 * PJ_PITCH] = (unsigned short)w3;
            d[7 * PJ_PITCH] = (unsigned short)(w3 >> 16);
        }
        __syncthreads();

#pragma unroll
        for (int nt = 0; nt < 16; nt++) {
            bf16x8 bfr = __builtin_bit_cast(bf16x8,
                *(const uint4*)(&Ds[(size_t)(nt * 16 + l15) * PJ_PITCH + quad * 8]));
            acc[nt] = __builtin_amdgcn_mfma_f32_16x16x32_bf16(wf[kc], bfr, acc[nt], 0, 0, 0);
        }
    }

    float* ob = out + (size_t)b * COUT * (T_ * N_);
#pragma unroll
    for (int nt = 0; nt < 16; nt++) {
        int n = n0 + nt * 16 + l15;
#pragma unroll
        for (int r = 0; r < 4; r++) {
            int o = wave * 16 + quad * 4 + r;
            ob[(size_t)o * (T_ * N_) + n] = acc[nt][r];
        }
    }
}

extern "C" void kernel_launch(void* const* d_in, const int* in_sizes, int n_in,
                              void* d_out, int out_size, void* d_ws, size_t ws_size,
                              hipStream_t stream) {
    const float* x  = (const float*)d_in[0];
    const float* La = (const float*)d_in[1];
    const float* W  = (const float*)d_in[2];
    float* out = (float*)d_out;

    const size_t n_x  = (size_t)B_ * CIN * T_ * N_;   // 33,554,432
    const size_t n_La = (size_t)B_ * N_ * N_;         //  4,194,304

    char* ws = (char*)d_ws;
    unsigned short* xb   = (unsigned short*)ws;                          // 64 MiB
    unsigned short* Lab  = (unsigned short*)(ws + n_x * 2);              //  8 MiB
    unsigned short* z1b  = (unsigned short*)(ws + n_x * 2 + n_La * 2);   // 64 MiB
    unsigned short* z2b  = (unsigned short*)(ws + n_x * 4 + n_La * 2);   // 64 MiB
    unsigned short* Wb   = (unsigned short*)(ws + n_x * 6 + n_La * 2);   // 24 KiB
    unsigned short* LaT  = (unsigned short*)(ws + n_x * 6 + n_La * 2 + (1 << 20));  // 8 MiB
    unsigned short* La2b = (unsigned short*)(ws + n_x * 6 + n_La * 4 + (1 << 20));  // 8 MiB

    cvt_f32_bf16<<<(int)(n_x / 2048), 256, 0, stream>>>(x, xb, (int)n_x);
    cvt_la_dual<<<dim3(8, 8, 16), 256, 0, stream>>>(La, Lab, LaT);
    pack_w<<<48, 256, 0, stream>>>(W, Wb);

    // La2[q][n] = (La@La)[q][n]  via NT: A=Lab (rows q), B=LaT (rows n)
    gemm_la2<<<256, 256, 0, stream>>>(Lab, LaT, La2b);

    // z1 = x@La^T ; z2 = 2*x@La2^T - x   (one fused dispatch, 2048 blocks)
    gemm_fused<<<2048, 256, 0, stream>>>(xb, Lab, La2b, z1b, z2b);

    dim3 gp((T_ * N_) / 256, B_);    // (128, 16)
    proj<<<gp, 256, 0, stream>>>(xb, z1b, z2b, Wb, out);
}